// Round 2
// baseline (876.064 us; speedup 1.0000x reference)
//
#include <hip/hip_runtime.h>
#include <cstdint>

#define NTOK 8192
#define CDIM 1024
#define HDIM 1408
#define HSDIM 2816
#define NEXP 8

typedef __attribute__((ext_vector_type(8))) short s8v;
typedef __attribute__((ext_vector_type(4))) float f4v;
typedef __attribute__((ext_vector_type(8))) unsigned short u16x8;

__device__ __forceinline__ unsigned short f2bf(float f) {
    unsigned int u = __float_as_uint(f);
    unsigned int r = (u + 0x7fffu + ((u >> 16) & 1u)) >> 16;  // RNE
    return (unsigned short)r;
}
__device__ __forceinline__ float bf2f(unsigned short u) {
    return __uint_as_float(((unsigned int)u) << 16);
}

__device__ __forceinline__ void gld_lds16(const unsigned short* g, unsigned short* l) {
    __builtin_amdgcn_global_load_lds(
        (const __attribute__((address_space(1))) void*)g,
        (__attribute__((address_space(3))) void*)l, 16, 0, 0);
}

// ---------------- conversion kernels ----------------

__global__ void cvt_bf16_kernel(const float4* __restrict__ in, ushort4* __restrict__ out, int n4) {
    int i = blockIdx.x * blockDim.x + threadIdx.x;
    if (i < n4) {
        float4 v = in[i];
        ushort4 o;
        o.x = f2bf(v.x); o.y = f2bf(v.y); o.z = f2bf(v.z); o.w = f2bf(v.w);
        out[i] = o;
    }
}

// 64x64 LDS-staged transpose+cvt: fp32 [z][R][Cc] -> bf16 [z][Cc][R].
__global__ __launch_bounds__(256) void transpose_cvt_kernel(
    const float* __restrict__ in0, const float* __restrict__ in1,
    unsigned short* __restrict__ out0, unsigned short* __restrict__ out1,
    int R, int Cc, int zsplit) {
    __shared__ float T[64][68];
    int z = blockIdx.z;
    const float* in = (z < zsplit) ? in0 : in1;
    unsigned short* out = (z < zsplit) ? out0 : out1;
    int zz = (z < zsplit) ? z : z - zsplit;
    const size_t bs = (size_t)R * Cc;
    in += zz * bs; out += zz * bs;

    const int t = threadIdx.x;
    const int r0 = blockIdx.y * 64, c0 = blockIdx.x * 64;

    {
        const int rl = t >> 2, cq = t & 3;
        const float* src = in + (size_t)(r0 + rl) * Cc + c0;
#pragma unroll
        for (int i = 0; i < 4; i++) {
            float4 v = *(const float4*)(src + (cq + 4 * i) * 4);
            *(float4*)&T[rl][(cq + 4 * i) * 4] = v;
        }
    }
    __syncthreads();
    {
        const int cl = t >> 2, rq = t & 3;
        unsigned short* dst = out + (size_t)(c0 + cl) * R + r0 + rq * 16;
        u16x8 lo, hi;
#pragma unroll
        for (int j = 0; j < 8; j++) lo[j] = f2bf(T[rq * 16 + j][cl]);
#pragma unroll
        for (int j = 0; j < 8; j++) hi[j] = f2bf(T[rq * 16 + 8 + j][cl]);
        *(u16x8*)dst = lo;
        *(u16x8*)(dst + 8) = hi;
    }
}

// ---------------- router ----------------
__global__ void router_kernel(const float* __restrict__ x, const float* __restrict__ Wg,
                              int* __restrict__ idxK, float* __restrict__ probK,
                              int* __restrict__ meta) {
    int t = blockIdx.x;
    int lane = threadIdx.x;
    const float* xr = x + (size_t)t * CDIM;
    float acc[NEXP];
#pragma unroll
    for (int e = 0; e < NEXP; e++) acc[e] = 0.f;
    for (int c = lane; c < CDIM; c += 64) {
        float xv = xr[c];
        const float* wr = Wg + c * NEXP;
#pragma unroll
        for (int e = 0; e < NEXP; e++) acc[e] += xv * wr[e];
    }
#pragma unroll
    for (int e = 0; e < NEXP; e++)
        for (int off = 32; off > 0; off >>= 1)
            acc[e] += __shfl_down(acc[e], off, 64);
    if (lane == 0) {
        int b0 = 0; float v0 = acc[0];
#pragma unroll
        for (int e = 1; e < NEXP; e++) if (acc[e] > v0) { v0 = acc[e]; b0 = e; }
        int b1 = -1; float v1 = -1e30f;
#pragma unroll
        for (int e = 0; e < NEXP; e++) if (e != b0 && acc[e] > v1) { v1 = acc[e]; b1 = e; }
        float p0 = 1.f / (1.f + __expf(v1 - v0));
        idxK[2 * t] = b0; idxK[2 * t + 1] = b1;
        probK[2 * t] = p0; probK[2 * t + 1] = 1.f - p0;
        atomicAdd(&meta[b0], 1);
        atomicAdd(&meta[b1], 1);
    }
}

// meta: [0..7] counts, [8..15] offsets, [16..23] cursor
__global__ void offsets_kernel(int* meta) {
    int s = 0;
    for (int e = 0; e < NEXP; e++) { meta[8 + e] = s; meta[16 + e] = s; s += meta[e]; }
}

__global__ void fill_kernel(const int* __restrict__ idxK, const float* __restrict__ probK,
                            int* __restrict__ meta, int* __restrict__ rowT, float* __restrict__ rowW,
                            int* __restrict__ tokSlot) {
    int t = blockIdx.x * 256 + threadIdx.x;
    if (t >= NTOK) return;
#pragma unroll
    for (int k = 0; k < 2; k++) {
        int e = idxK[2 * t + k];
        int p = atomicAdd(&meta[16 + e], 1);
        rowT[p] = t;
        rowW[p] = probK[2 * t + k];
        tokSlot[2 * t + k] = p;
    }
}

// ---------------- merged fused gate GEMM: H = silu(A@W1) * (A@W2) ----------------
// 8-phase-style schedule (T3+T4+T5): BM=256, BN=64 (dual-B), BK=64, 512 thr,
// 96 KB LDS double-buffered. Counted vmcnt(2) at half-tile boundaries (never 0
// in the loop); staging targets regions dead behind the read front.
// LDS layout per slot (shorts): A half0 [0,8192), A half1 [8192,16384),
// B1 [16384,20480), B2 [20480,24576). Rows stored [row][64] with chunk-XOR
// swizzle carried on the GLOBAL source (read chunk = (q*4+quad)^(row&7)).
__global__ __launch_bounds__(512) void gemm12_kernel(
    const unsigned short* __restrict__ xb,
    const unsigned short* __restrict__ w1, const unsigned short* __restrict__ w2,
    const unsigned short* __restrict__ ws1, const unsigned short* __restrict__ ws2,
    unsigned short* __restrict__ hE, unsigned short* __restrict__ hS,
    const int* __restrict__ rowT, const int* __restrict__ meta) {
    const int id = blockIdx.x;
    int z, m0, n0; bool SH;
    if (id < 1760) { SH = false; z = id & 7; int q = id >> 3; m0 = (q % 10) * 256; n0 = (q / 10) * 64; }
    else           { SH = true;  z = 8; int q = id - 1760; m0 = (q & 31) * 256; n0 = (q >> 5) * 64; }
    const int M = SH ? NTOK : meta[z];
    const int base = SH ? 0 : meta[8 + z];
    if (m0 >= M) return;

    const unsigned short* B1 = SH ? ws1 : w1 + (size_t)z * HDIM * CDIM;
    const unsigned short* B2 = SH ? ws2 : w2 + (size_t)z * HDIM * CDIM;

    __shared__ unsigned short L[49152];  // 96 KB

    const int tid = threadIdx.x;
    const int trow = tid >> 3;                       // 0..63
    const int colg = ((tid & 7) ^ (trow & 7)) << 3;  // swizzled global chunk (shorts)

    // 4 A-row pointers (rows m0+trow+{0,64,128,192}), clamped, via rowT for experts
    int r0 = m0 + trow, r1 = m0 + 64 + trow, r2 = m0 + 128 + trow, r3 = m0 + 192 + trow;
    r0 = r0 < M ? r0 : M - 1; r1 = r1 < M ? r1 : M - 1;
    r2 = r2 < M ? r2 : M - 1; r3 = r3 < M ? r3 : M - 1;
    const int g0 = SH ? r0 : rowT[base + r0];
    const int g1 = SH ? r1 : rowT[base + r1];
    const int g2 = SH ? r2 : rowT[base + r2];
    const int g3 = SH ? r3 : rowT[base + r3];
    const unsigned short* gA0 = xb + (size_t)g0 * CDIM + colg;
    const unsigned short* gA1 = xb + (size_t)g1 * CDIM + colg;
    const unsigned short* gA2 = xb + (size_t)g2 * CDIM + colg;
    const unsigned short* gA3 = xb + (size_t)g3 * CDIM + colg;
    const unsigned short* gB1 = B1 + (size_t)(n0 + trow) * CDIM + colg;
    const unsigned short* gB2 = B2 + (size_t)(n0 + trow) * CDIM + colg;

    const int w = tid >> 6, lane = tid & 63;
    const int wq = w >> 1;             // m-group 0..3 (32 rows per half)
    const int wn = (w & 1) * 32;       // n-offset
    const int quad = lane >> 4, l15 = lane & 15;
    const int kxor = l15 & 7;
    int cX[2];
    cX[0] = (quad ^ kxor) << 3;
    cX[1] = ((4 + quad) ^ kxor) << 3;
    int roA[2], roB[2];
    roA[0] = (wq * 32 + l15) * 64; roA[1] = roA[0] + 16 * 64;
    roB[0] = (wn + l15) * 64;      roB[1] = roB[0] + 16 * 64;

    f4v acc1[4][2], acc2[4][2];
#pragma unroll
    for (int i = 0; i < 4; i++)
#pragma unroll
        for (int j = 0; j < 2; j++) {
            f4v zz = {0.f, 0.f, 0.f, 0.f};
            acc1[i][j] = zz; acc2[i][j] = zz;
        }

    s8v bq1[2][2], bq2[2][2], af[2][2];

    auto ST_A0 = [&](int s, int t) {
        gld_lds16(gA0 + (size_t)t * 64, L + s * 24576 + tid * 8);
        gld_lds16(gA1 + (size_t)t * 64, L + s * 24576 + 4096 + tid * 8);
    };
    auto ST_A1 = [&](int s, int t) {
        gld_lds16(gA2 + (size_t)t * 64, L + s * 24576 + 8192 + tid * 8);
        gld_lds16(gA3 + (size_t)t * 64, L + s * 24576 + 12288 + tid * 8);
    };
    auto ST_B = [&](int s, int t) {
        gld_lds16(gB1 + (size_t)t * 64, L + s * 24576 + 16384 + tid * 8);
        gld_lds16(gB2 + (size_t)t * 64, L + s * 24576 + 20480 + tid * 8);
    };
    auto READB = [&](int s) {
        const unsigned short* B1s = L + s * 24576 + 16384;
        const unsigned short* B2s = L + s * 24576 + 20480;
#pragma unroll
        for (int q = 0; q < 2; q++)
#pragma unroll
            for (int nt = 0; nt < 2; nt++) {
                bq1[q][nt] = *(const s8v*)(B1s + roB[nt] + cX[q]);
                bq2[q][nt] = *(const s8v*)(B2s + roB[nt] + cX[q]);
            }
    };
    auto READA = [&](int s, int h) {
        const unsigned short* As = L + s * 24576 + h * 8192;
#pragma unroll
        for (int q = 0; q < 2; q++)
#pragma unroll
            for (int mt = 0; mt < 2; mt++)
                af[q][mt] = *(const s8v*)(As + roA[mt] + cX[q]);
    };
    auto MFMA16 = [&](int h) {
#pragma unroll
        for (int q = 0; q < 2; q++)
#pragma unroll
            for (int mt = 0; mt < 2; mt++)
#pragma unroll
                for (int nt = 0; nt < 2; nt++) {
                    acc1[h * 2 + mt][nt] = __builtin_amdgcn_mfma_f32_16x16x32_bf16(
                        af[q][mt], bq1[q][nt], acc1[h * 2 + mt][nt], 0, 0, 0);
                    acc2[h * 2 + mt][nt] = __builtin_amdgcn_mfma_f32_16x16x32_bf16(
                        af[q][mt], bq2[q][nt], acc2[h * 2 + mt][nt], 0, 0, 0);
                }
    };

    // prologue: tile0 -> slot0 fully, A0 of tile1 -> slot1
    ST_A0(0, 0); ST_A1(0, 0); ST_B(0, 0); ST_A0(1, 1);
    asm volatile("s_waitcnt vmcnt(2)");
    __builtin_amdgcn_sched_barrier(0);
    __builtin_amdgcn_s_barrier();

    // 16 K-tiles, 2 per iteration (slot0 then slot1), 2 phases per tile.
#pragma unroll 1
    for (int i = 0; i < 8; i++) {
        const int t1 = 2 * i + 1;
        const int t2 = (2 * i + 2 < 16) ? 2 * i + 2 : 15;
        const int t3 = (2 * i + 3 < 16) ? 2 * i + 3 : 15;
        // P1: tile t0 (slot0), rows half0
        READB(0); READA(0, 0);
        ST_A1(1, t1);
        __builtin_amdgcn_s_barrier();
        __builtin_amdgcn_s_setprio(1); MFMA16(0); __builtin_amdgcn_s_setprio(0);
        __builtin_amdgcn_s_barrier();
        // P2: tile t0, rows half1
        READA(0, 1);
        ST_B(1, t1); ST_A0(0, t2);
        __builtin_amdgcn_s_barrier();
        __builtin_amdgcn_s_setprio(1); MFMA16(1); __builtin_amdgcn_s_setprio(0);
        asm volatile("s_waitcnt vmcnt(2)");
        __builtin_amdgcn_sched_barrier(0);
        __builtin_amdgcn_s_barrier();
        // P3: tile t1 (slot1), rows half0
        READB(1); READA(1, 0);
        ST_A1(0, t2); ST_B(0, t2);
        __builtin_amdgcn_s_barrier();
        __builtin_amdgcn_s_setprio(1); MFMA16(0); __builtin_amdgcn_s_setprio(0);
        __builtin_amdgcn_s_barrier();
        // P4: tile t1, rows half1
        READA(1, 1);
        ST_A0(1, t3);
        __builtin_amdgcn_s_barrier();
        __builtin_amdgcn_s_setprio(1); MFMA16(1); __builtin_amdgcn_s_setprio(0);
        asm volatile("s_waitcnt vmcnt(2)");
        __builtin_amdgcn_sched_barrier(0);
        __builtin_amdgcn_s_barrier();
    }
    asm volatile("s_waitcnt vmcnt(0)");  // drain before LDS teardown

#pragma unroll
    for (int h = 0; h < 2; h++)
#pragma unroll
        for (int mt = 0; mt < 2; mt++)
#pragma unroll
            for (int r = 0; r < 4; r++) {
                int gm = m0 + h * 128 + wq * 32 + mt * 16 + quad * 4 + r;
                if (gm < M) {
                    unsigned short* hrow = SH ? hS + (size_t)gm * HSDIM
                                              : hE + (size_t)(base + gm) * HDIM;
#pragma unroll
                    for (int nt = 0; nt < 2; nt++) {
                        float z1 = acc1[h * 2 + mt][nt][r];
                        float z2 = acc2[h * 2 + mt][nt][r];
                        float hv = (z1 / (1.f + __expf(-z1))) * z2;
                        hrow[n0 + wn + nt * 16 + l15] = f2bf(hv);
                    }
                }
            }
}

// ---------------- merged down-proj GEMM (R1-verified form) ----------------
__global__ __launch_bounds__(256) void gemm3_kernel(
    const unsigned short* __restrict__ hE, const unsigned short* __restrict__ hS,
    const unsigned short* __restrict__ w3, const unsigned short* __restrict__ ws3,
    float* __restrict__ Out, unsigned short* __restrict__ pE,
    const int* __restrict__ rowT, const float* __restrict__ rowW, const int* __restrict__ meta) {
    const int id = blockIdx.x;
    int z, m0, n0; bool SH;
    if (id < 1280) { SH = false; z = id & 7; int q = id >> 3; m0 = (q % 20) * 128; n0 = (q / 20) * 128; }
    else           { SH = true;  z = 8; int q = id - 1280; m0 = (q & 63) * 128; n0 = (q >> 6) * 128; }
    const int M = SH ? NTOK : meta[z];
    const int base = SH ? 0 : meta[8 + z];
    if (m0 >= M) return;
    const int K = SH ? HSDIM : HDIM;
    const unsigned short* A = SH ? hS : hE;
    const unsigned short* B = SH ? ws3 : w3 + (size_t)z * CDIM * HDIM;

    __shared__ unsigned short L[16384];

    const int tid = threadIdx.x;
    const int srow = tid >> 2;
    const int key = (tid >> 3) & 3;
    const int co = ((tid & 3) ^ key) << 3;

    int am0 = m0 + srow;       am0 = am0 < M ? am0 : M - 1;
    int am1 = m0 + 64 + srow;  am1 = am1 < M ? am1 : M - 1;
    const unsigned short* a0p = A + (size_t)(base + am0) * K + co;
    const unsigned short* a1p = A + (size_t)(base + am1) * K + co;
    const unsigned short* b0p = B + (size_t)(n0 + srow) * K + co;
    const unsigned short* b1p = B + (size_t)(n0 + 64 + srow) * K + co;

    const int w = tid >> 6, lane = tid & 63;
    const int wm = (w >> 1) * 64, wn = (w & 1) * 64;
    const int quad = lane >> 4, l15 = lane & 15;
    const int rcx = (quad ^ ((l15 >> 1) & 3)) << 3;

    f4v acc[4][4];
#pragma unroll
    for (int i = 0; i < 4; i++)
#pragma unroll
        for (int j = 0; j < 4; j++) {
            f4v zz = {0.f, 0.f, 0.f, 0.f};
            acc[i][j] = zz;
        }

#define STAGE3(b, k0) do { \
        gld_lds16(a0p + (k0), L + (b) * 4096 + tid * 8); \
        gld_lds16(a1p + (k0), L + (b) * 4096 + 2048 + tid * 8); \
        gld_lds16(b0p + (k0), L + 8192 + (b) * 4096 + tid * 8); \
        gld_lds16(b1p + (k0), L + 8192 + (b) * 4096 + 2048 + tid * 8); } while (0)

    auto compute = [&](int b) {
        const unsigned short* Ab = L + b * 4096;
        const unsigned short* Bb = L + 8192 + b * 4096;
        s8v af[4], bf[4];
#pragma unroll
        for (int mt = 0; mt < 4; mt++)
            af[mt] = *(const s8v*)(Ab + (wm + mt * 16 + l15) * 32 + rcx);
#pragma unroll
        for (int nt = 0; nt < 4; nt++)
            bf[nt] = *(const s8v*)(Bb + (wn + nt * 16 + l15) * 32 + rcx);
#pragma unroll
        for (int mt = 0; mt < 4; mt++)
#pragma unroll
            for (int nt = 0; nt < 4; nt++)
                acc[mt][nt] = __builtin_amdgcn_mfma_f32_16x16x32_bf16(af[mt], bf[nt], acc[mt][nt], 0, 0, 0);
    };

    const int NS = K / 32;
    STAGE3(0, 0);
    __syncthreads();
#pragma unroll 1
    for (int ks = 0; ks < NS; ks++) {
        if (ks + 1 < NS) STAGE3((ks + 1) & 1, (ks + 1) * 32);
        compute(ks & 1);
        __syncthreads();
    }
#undef STAGE3

#pragma unroll
    for (int mt = 0; mt < 4; mt++) {
#pragma unroll
        for (int r = 0; r < 4; r++) {
            int gm = m0 + wm + mt * 16 + quad * 4 + r;
            if (gm < M) {
                if (SH) {
                    size_t o = (size_t)gm * CDIM + n0 + wn + l15;
#pragma unroll
                    for (int nt = 0; nt < 4; nt++)
                        Out[o + nt * 16] = acc[mt][nt][r];
                } else {
                    size_t o = (size_t)(base + gm) * CDIM + n0 + wn + l15;
#pragma unroll
                    for (int nt = 0; nt < 4; nt++)
                        pE[o + nt * 16] = f2bf(acc[mt][nt][r]);
                }
            }
        }
    }
}

// ---------------- combine: out[t] += w0*pE[s0] + w1*pE[s1] ----------------
__global__ __launch_bounds__(256) void combine_kernel(
    float* __restrict__ Out, const unsigned short* __restrict__ pE,
    const int* __restrict__ tokSlot, const float* __restrict__ rowW) {
    const int t = blockIdx.x;
    const int c = threadIdx.x * 4;
    const int s0 = tokSlot[2 * t], s1 = tokSlot[2 * t + 1];
    const float w0 = rowW[s0], w1 = rowW[s1];
    float* op = Out + (size_t)t * CDIM + c;
    float4 o = *(float4*)op;
    ushort4 a = *(const ushort4*)(pE + (size_t)s0 * CDIM + c);
    ushort4 b = *(const ushort4*)(pE + (size_t)s1 * CDIM + c);
    o.x += w0 * bf2f(a.x) + w1 * bf2f(b.x);
    o.y += w0 * bf2f(a.y) + w1 * bf2f(b.y);
    o.z += w0 * bf2f(a.z) + w1 * bf2f(b.z);
    o.w += w0 * bf2f(a.w) + w1 * bf2f(b.w);
    *(float4*)op = o;
}

// ---------------- launch ----------------

extern "C" void kernel_launch(void* const* d_in, const int* in_sizes, int n_in,
                              void* d_out, int out_size, void* d_ws, size_t ws_size,
                              hipStream_t stream) {
    const float* x   = (const float*)d_in[0];
    const float* Wg  = (const float*)d_in[1];
    const float* W1  = (const float*)d_in[2];
    const float* W2  = (const float*)d_in[3];
    const float* W3  = (const float*)d_in[4];
    const float* Ws1 = (const float*)d_in[5];
    const float* Ws2 = (const float*)d_in[6];
    const float* Ws3 = (const float*)d_in[7];
    float* out = (float*)d_out;

    char* p = (char*)d_ws;
    auto carve = [&](size_t bytes) {
        char* r = p;
        p += (bytes + 255) & ~(size_t)255;
        return r;
    };
    unsigned short* xb   = (unsigned short*)carve((size_t)NTOK * CDIM * 2);
    unsigned short* w1t  = (unsigned short*)carve((size_t)NEXP * HDIM * CDIM * 2);
    unsigned short* w2t  = (unsigned short*)carve((size_t)NEXP * HDIM * CDIM * 2);
    unsigned short* w3t  = (unsigned short*)carve((size_t)NEXP * CDIM * HDIM * 2);
    unsigned short* ws1t = (unsigned short*)carve((size_t)HSDIM * CDIM * 2);
    unsigned short* ws2t = (unsigned short*)carve((size_t)HSDIM * CDIM * 2);
    unsigned short* ws3t = (unsigned short*)carve((size_t)CDIM * HSDIM * 2);
    unsigned short* hE   = (unsigned short*)carve((size_t)2 * NTOK * HDIM * 2);
    unsigned short* hS   = (unsigned short*)carve((size_t)NTOK * HSDIM * 2);
    int*   idxK   = (int*)carve((size_t)NTOK * 2 * 4);
    float* probK  = (float*)carve((size_t)NTOK * 2 * 4);
    int*   rowT   = (int*)carve((size_t)2 * NTOK * 4);
    float* rowW   = (float*)carve((size_t)2 * NTOK * 4);
    int*   tokSlot= (int*)carve((size_t)2 * NTOK * 4);
    int*   meta   = (int*)carve(256);

    // expert partials (bf16, 2N x C = 33.5 MB) alias the w1t+w2t region,
    // which is dead after gemm12 completes (stream-ordered before gemm3).
    unsigned short* pE = w1t;

    cvt_bf16_kernel<<<(NTOK * CDIM / 4 + 255) / 256, 256, 0, stream>>>(
        (const float4*)x, (ushort4*)xb, NTOK * CDIM / 4);
    transpose_cvt_kernel<<<dim3(HDIM / 64, CDIM / 64, 16), 256, 0, stream>>>(
        W1, W2, w1t, w2t, CDIM, HDIM, 8);
    transpose_cvt_kernel<<<dim3(CDIM / 64, HDIM / 64, 8), 256, 0, stream>>>(
        W3, W3, w3t, w3t, HDIM, CDIM, 8);
    transpose_cvt_kernel<<<dim3(HSDIM / 64, CDIM / 64, 2), 256, 0, stream>>>(
        Ws1, Ws2, ws1t, ws2t, CDIM, HSDIM, 1);
    transpose_cvt_kernel<<<dim3(CDIM / 64, HSDIM / 64, 1), 256, 0, stream>>>(
        Ws3, Ws3, ws3t, ws3t, HSDIM, CDIM, 1);

    hipMemsetAsync(meta, 0, 256, stream);
    router_kernel<<<NTOK, 64, 0, stream>>>(x, Wg, idxK, probK, meta);
    offsets_kernel<<<1, 1, 0, stream>>>(meta);
    fill_kernel<<<NTOK / 256, 256, 0, stream>>>(idxK, probK, meta, rowT, rowW, tokSlot);

    gemm12_kernel<<<1760 + 1408, 512, 0, stream>>>(
        xb, w1t, w2t, ws1t, ws2t, hE, hS, rowT, meta);
    gemm3_kernel<<<1280 + 512, 256, 0, stream>>>(
        hE, hS, w3t, ws3t, out, pE, rowT, rowW, meta);
    combine_kernel<<<NTOK, 256, 0, stream>>>(out, pE, tokSlot, rowW);
}

// Round 3
// 826.434 us; speedup vs baseline: 1.0601x; 1.0601x over previous
//
#include <hip/hip_runtime.h>
#include <cstdint>

#define NTOK 8192
#define CDIM 1024
#define HDIM 1408
#define HSDIM 2816
#define NEXP 8

typedef __attribute__((ext_vector_type(8))) short s8v;
typedef __attribute__((ext_vector_type(4))) float f4v;
typedef __attribute__((ext_vector_type(8))) unsigned short u16x8;

__device__ __forceinline__ unsigned short f2bf(float f) {
    unsigned int u = __float_as_uint(f);
    unsigned int r = (u + 0x7fffu + ((u >> 16) & 1u)) >> 16;  // RNE
    return (unsigned short)r;
}
__device__ __forceinline__ float bf2f(unsigned short u) {
    return __uint_as_float(((unsigned int)u) << 16);
}

__device__ __forceinline__ void gld_lds16(const unsigned short* g, unsigned short* l) {
    __builtin_amdgcn_global_load_lds(
        (const __attribute__((address_space(1))) void*)g,
        (__attribute__((address_space(3))) void*)l, 16, 0, 0);
}

// ---------------- fused prep kernel ----------------
// One launch covering: router (wave/token), x->bf16 cvt, and all 4 weight
// transposes. All parts are independent; selected by blockIdx range.

#define P_RTR 2048                  // 8192 tokens, 4 waves/block
#define P_CVT 8192                  // NTOK*CDIM/4 float4 / 256
#define P_T1 (22 * 16 * 16)         // W1,W2 (5632)
#define P_T2 (16 * 22 * 8)          // W3 (2816)
#define P_T3 (44 * 16 * 2)          // Ws1,Ws2 (1408)
#define P_T4 (16 * 44 * 1)          // Ws3 (704)
#define P_TOTAL (P_RTR + P_CVT + P_T1 + P_T2 + P_T3 + P_T4)

__device__ __forceinline__ void transpose_tile(
    float (*T)[68], const float* __restrict__ in, unsigned short* __restrict__ out,
    int R, int Cc, int bx, int by) {
    const int t = threadIdx.x;
    const int r0 = by * 64, c0 = bx * 64;
    {
        const int rl = t >> 2, cq = t & 3;
        const float* src = in + (size_t)(r0 + rl) * Cc + c0;
#pragma unroll
        for (int i = 0; i < 4; i++) {
            float4 v = *(const float4*)(src + (cq + 4 * i) * 4);
            *(float4*)&T[rl][(cq + 4 * i) * 4] = v;
        }
    }
    __syncthreads();
    {
        const int cl = t >> 2, rq = t & 3;
        unsigned short* dst = out + (size_t)(c0 + cl) * R + r0 + rq * 16;
        u16x8 lo, hi;
#pragma unroll
        for (int j = 0; j < 8; j++) lo[j] = f2bf(T[rq * 16 + j][cl]);
#pragma unroll
        for (int j = 0; j < 8; j++) hi[j] = f2bf(T[rq * 16 + 8 + j][cl]);
        *(u16x8*)dst = lo;
        *(u16x8*)(dst + 8) = hi;
    }
}

__global__ __launch_bounds__(256) void prep_kernel(
    const float* __restrict__ x, const float* __restrict__ Wg,
    const float* __restrict__ W1, const float* __restrict__ W2, const float* __restrict__ W3,
    const float* __restrict__ Ws1, const float* __restrict__ Ws2, const float* __restrict__ Ws3,
    unsigned short* __restrict__ xb,
    unsigned short* __restrict__ w1t, unsigned short* __restrict__ w2t,
    unsigned short* __restrict__ w3t,
    unsigned short* __restrict__ ws1t, unsigned short* __restrict__ ws2t,
    unsigned short* __restrict__ ws3t,
    int* __restrict__ idxK, float* __restrict__ probK, int* __restrict__ meta) {
    __shared__ float T[64][68];
    int bid = blockIdx.x;
    const int tid = threadIdx.x;

    if (bid < P_RTR) {
        // ---- router: one wave per token ----
        const int t = bid * 4 + (tid >> 6);
        const int lane = tid & 63;
        const float* xr = x + (size_t)t * CDIM;
        float acc[NEXP];
#pragma unroll
        for (int e = 0; e < NEXP; e++) acc[e] = 0.f;
        for (int c = lane; c < CDIM; c += 64) {
            float xv = xr[c];
            const float* wr = Wg + c * NEXP;
#pragma unroll
            for (int e = 0; e < NEXP; e++) acc[e] += xv * wr[e];
        }
#pragma unroll
        for (int e = 0; e < NEXP; e++)
            for (int off = 32; off > 0; off >>= 1)
                acc[e] += __shfl_down(acc[e], off, 64);
        if (lane == 0) {
            int b0 = 0; float v0 = acc[0];
#pragma unroll
            for (int e = 1; e < NEXP; e++) if (acc[e] > v0) { v0 = acc[e]; b0 = e; }
            int b1 = -1; float v1 = -1e30f;
#pragma unroll
            for (int e = 0; e < NEXP; e++) if (e != b0 && acc[e] > v1) { v1 = acc[e]; b1 = e; }
            float p0 = 1.f / (1.f + __expf(v1 - v0));
            idxK[2 * t] = b0; idxK[2 * t + 1] = b1;
            probK[2 * t] = p0; probK[2 * t + 1] = 1.f - p0;
            atomicAdd(&meta[b0], 1);
            atomicAdd(&meta[b1], 1);
        }
        return;
    }
    bid -= P_RTR;
    if (bid < P_CVT) {
        // ---- x -> bf16 ----
        const int i = bid * 256 + tid;
        float4 v = ((const float4*)x)[i];
        ushort4 o;
        o.x = f2bf(v.x); o.y = f2bf(v.y); o.z = f2bf(v.z); o.w = f2bf(v.w);
        ((ushort4*)xb)[i] = o;
        return;
    }
    bid -= P_CVT;
    if (bid < P_T1) {
        // ---- W1/W2 [e][C][H] -> [e][H][C] ----
        const int bx = bid % 22, by = (bid / 22) % 16, z = bid / (22 * 16);
        const float* in = (z < 8) ? W1 : W2;
        unsigned short* out = (z < 8) ? w1t : w2t;
        const int zz = (z < 8) ? z : z - 8;
        const size_t bs = (size_t)CDIM * HDIM;
        transpose_tile(T, in + zz * bs, out + zz * bs, CDIM, HDIM, bx, by);
        return;
    }
    bid -= P_T1;
    if (bid < P_T2) {
        // ---- W3 [e][H][C] -> [e][C][H] ----
        const int bx = bid % 16, by = (bid / 16) % 22, z = bid / (16 * 22);
        const size_t bs = (size_t)HDIM * CDIM;
        transpose_tile(T, W3 + z * bs, w3t + z * bs, HDIM, CDIM, bx, by);
        return;
    }
    bid -= P_T2;
    if (bid < P_T3) {
        // ---- Ws1/Ws2 [C][HS] -> [HS][C] ----
        const int bx = bid % 44, by = (bid / 44) % 16, z = bid / (44 * 16);
        const float* in = (z == 0) ? Ws1 : Ws2;
        unsigned short* out = (z == 0) ? ws1t : ws2t;
        transpose_tile(T, in, out, CDIM, HSDIM, bx, by);
        return;
    }
    bid -= P_T3;
    {
        // ---- Ws3 [HS][C] -> [C][HS] ----
        const int bx = bid % 16, by = bid / 16;
        transpose_tile(T, Ws3, ws3t, HSDIM, CDIM, bx, by);
    }
}

// meta: [0..7] counts, [8..15] offsets, [16..23] cursor
__global__ void offsets_kernel(int* meta) {
    int s = 0;
    for (int e = 0; e < NEXP; e++) { meta[8 + e] = s; meta[16 + e] = s; s += meta[e]; }
}

__global__ void fill_kernel(const int* __restrict__ idxK, const float* __restrict__ probK,
                            int* __restrict__ meta, int* __restrict__ rowT, float* __restrict__ rowW,
                            int* __restrict__ tokSlot) {
    int t = blockIdx.x * 256 + threadIdx.x;
    if (t >= NTOK) return;
#pragma unroll
    for (int k = 0; k < 2; k++) {
        int e = idxK[2 * t + k];
        int p = atomicAdd(&meta[16 + e], 1);
        rowT[p] = t;
        rowW[p] = probK[2 * t + k];
        tokSlot[2 * t + k] = p;
    }
}

// ---------------- merged fused gate GEMM: H = silu(A@W1) * (A@W2) ----------------
// R1-verified form: BM=128, BN=64, BK=32, global_load_lds staging (m97
// structure): LDS dest linear in tid, bank-swizzle carried on global source.
__global__ __launch_bounds__(256) void gemm12_kernel(
    const unsigned short* __restrict__ xb,
    const unsigned short* __restrict__ w1, const unsigned short* __restrict__ w2,
    const unsigned short* __restrict__ ws1, const unsigned short* __restrict__ ws2,
    unsigned short* __restrict__ hE, unsigned short* __restrict__ hS,
    const int* __restrict__ rowT, const int* __restrict__ meta) {
    const int id = blockIdx.x;
    int z, m0, n0; bool SH;
    if (id < 3520) { SH = false; z = id & 7; int q = id >> 3; m0 = (q % 20) * 128; n0 = (q / 20) * 64; }
    else           { SH = true;  z = 8; int q = id - 3520; m0 = (q & 63) * 128; n0 = (q >> 6) * 64; }
    const int M = SH ? NTOK : meta[z];
    const int base = SH ? 0 : meta[8 + z];
    if (m0 >= M) return;

    const unsigned short* B1 = SH ? ws1 : w1 + (size_t)z * HDIM * CDIM;
    const unsigned short* B2 = SH ? ws2 : w2 + (size_t)z * HDIM * CDIM;

    __shared__ unsigned short L[16384];  // 32 KB

    const int tid = threadIdx.x;
    const int srow = tid >> 2;
    const int key = (tid >> 3) & 3;
    const int co = ((tid & 3) ^ key) << 3;

    int am0 = m0 + srow;       am0 = am0 < M ? am0 : M - 1;
    int am1 = m0 + 64 + srow;  am1 = am1 < M ? am1 : M - 1;
    long ar0 = SH ? am0 : rowT[base + am0];
    long ar1 = SH ? am1 : rowT[base + am1];
    const unsigned short* a0p = xb + (size_t)ar0 * CDIM + co;
    const unsigned short* a1p = xb + (size_t)ar1 * CDIM + co;
    const unsigned short* b1p = B1 + (size_t)(n0 + srow) * CDIM + co;
    const unsigned short* b2p = B2 + (size_t)(n0 + srow) * CDIM + co;

    const int w = tid >> 6, lane = tid & 63;
    const int wm = (w >> 1) * 64, wn = (w & 1) * 32;
    const int quad = lane >> 4, l15 = lane & 15;
    const int rcx = (quad ^ ((l15 >> 1) & 3)) << 3;

    f4v acc1[4][2], acc2[4][2];
#pragma unroll
    for (int i = 0; i < 4; i++)
#pragma unroll
        for (int j = 0; j < 2; j++) {
            f4v zz = {0.f, 0.f, 0.f, 0.f};
            acc1[i][j] = zz; acc2[i][j] = zz;
        }

#define STAGE12(b, k0) do { \
        gld_lds16(a0p + (k0), L + (b) * 4096 + tid * 8); \
        gld_lds16(a1p + (k0), L + (b) * 4096 + 2048 + tid * 8); \
        gld_lds16(b1p + (k0), L + 8192 + (b) * 2048 + tid * 8); \
        gld_lds16(b2p + (k0), L + 12288 + (b) * 2048 + tid * 8); } while (0)

    auto compute = [&](int b) {
        const unsigned short* Ab = L + b * 4096;
        const unsigned short* B1b = L + 8192 + b * 2048;
        const unsigned short* B2b = L + 12288 + b * 2048;
        s8v af[4], bf1[2], bf2[2];
#pragma unroll
        for (int mt = 0; mt < 4; mt++)
            af[mt] = *(const s8v*)(Ab + (wm + mt * 16 + l15) * 32 + rcx);
#pragma unroll
        for (int nt = 0; nt < 2; nt++) {
            bf1[nt] = *(const s8v*)(B1b + (wn + nt * 16 + l15) * 32 + rcx);
            bf2[nt] = *(const s8v*)(B2b + (wn + nt * 16 + l15) * 32 + rcx);
        }
#pragma unroll
        for (int mt = 0; mt < 4; mt++)
#pragma unroll
            for (int nt = 0; nt < 2; nt++) {
                acc1[mt][nt] = __builtin_amdgcn_mfma_f32_16x16x32_bf16(af[mt], bf1[nt], acc1[mt][nt], 0, 0, 0);
                acc2[mt][nt] = __builtin_amdgcn_mfma_f32_16x16x32_bf16(af[mt], bf2[nt], acc2[mt][nt], 0, 0, 0);
            }
    };

    const int NS = CDIM / 32;
    STAGE12(0, 0);
    __syncthreads();
#pragma unroll 1
    for (int ks = 0; ks < NS; ks++) {
        if (ks + 1 < NS) STAGE12((ks + 1) & 1, (ks + 1) * 32);
        compute(ks & 1);
        __syncthreads();
    }
#undef STAGE12

#pragma unroll
    for (int mt = 0; mt < 4; mt++) {
#pragma unroll
        for (int r = 0; r < 4; r++) {
            int gm = m0 + wm + mt * 16 + quad * 4 + r;
            if (gm < M) {
                unsigned short* hrow = SH ? hS + (size_t)gm * HSDIM
                                          : hE + (size_t)(base + gm) * HDIM;
#pragma unroll
                for (int nt = 0; nt < 2; nt++) {
                    float z1 = acc1[mt][nt][r];
                    float z2 = acc2[mt][nt][r];
                    float hv = (z1 / (1.f + __expf(-z1))) * z2;
                    hrow[n0 + wn + nt * 16 + l15] = f2bf(hv);
                }
            }
        }
    }
}

// ---------------- merged down-proj GEMM ----------------
// Longest-job-first: shared blocks (K=2816, 2x work) dispatch at ids [0,512),
// experts after. z<8: expert -> plain bf16 stores to pE. shared -> fp32 Out.
__global__ __launch_bounds__(256) void gemm3_kernel(
    const unsigned short* __restrict__ hE, const unsigned short* __restrict__ hS,
    const unsigned short* __restrict__ w3, const unsigned short* __restrict__ ws3,
    float* __restrict__ Out, unsigned short* __restrict__ pE,
    const int* __restrict__ rowT, const float* __restrict__ rowW, const int* __restrict__ meta) {
    const int id = blockIdx.x;
    int z, m0, n0; bool SH;
    if (id < 512) { SH = true;  z = 8; int q = id; m0 = (q & 63) * 128; n0 = (q >> 6) * 128; }
    else          { SH = false; int r = id - 512; z = r & 7; int q = r >> 3; m0 = (q % 20) * 128; n0 = (q / 20) * 128; }
    const int M = SH ? NTOK : meta[z];
    const int base = SH ? 0 : meta[8 + z];
    if (m0 >= M) return;
    const int K = SH ? HSDIM : HDIM;
    const unsigned short* A = SH ? hS : hE;
    const unsigned short* B = SH ? ws3 : w3 + (size_t)z * CDIM * HDIM;

    __shared__ unsigned short L[16384];

    const int tid = threadIdx.x;
    const int srow = tid >> 2;
    const int key = (tid >> 3) & 3;
    const int co = ((tid & 3) ^ key) << 3;

    int am0 = m0 + srow;       am0 = am0 < M ? am0 : M - 1;
    int am1 = m0 + 64 + srow;  am1 = am1 < M ? am1 : M - 1;
    const unsigned short* a0p = A + (size_t)(base + am0) * K + co;
    const unsigned short* a1p = A + (size_t)(base + am1) * K + co;
    const unsigned short* b0p = B + (size_t)(n0 + srow) * K + co;
    const unsigned short* b1p = B + (size_t)(n0 + 64 + srow) * K + co;

    const int w = tid >> 6, lane = tid & 63;
    const int wm = (w >> 1) * 64, wn = (w & 1) * 64;
    const int quad = lane >> 4, l15 = lane & 15;
    const int rcx = (quad ^ ((l15 >> 1) & 3)) << 3;

    f4v acc[4][4];
#pragma unroll
    for (int i = 0; i < 4; i++)
#pragma unroll
        for (int j = 0; j < 4; j++) {
            f4v zz = {0.f, 0.f, 0.f, 0.f};
            acc[i][j] = zz;
        }

#define STAGE3(b, k0) do { \
        gld_lds16(a0p + (k0), L + (b) * 4096 + tid * 8); \
        gld_lds16(a1p + (k0), L + (b) * 4096 + 2048 + tid * 8); \
        gld_lds16(b0p + (k0), L + 8192 + (b) * 4096 + tid * 8); \
        gld_lds16(b1p + (k0), L + 8192 + (b) * 4096 + 2048 + tid * 8); } while (0)

    auto compute = [&](int b) {
        const unsigned short* Ab = L + b * 4096;
        const unsigned short* Bb = L + 8192 + b * 4096;
        s8v af[4], bf[4];
#pragma unroll
        for (int mt = 0; mt < 4; mt++)
            af[mt] = *(const s8v*)(Ab + (wm + mt * 16 + l15) * 32 + rcx);
#pragma unroll
        for (int nt = 0; nt < 4; nt++)
            bf[nt] = *(const s8v*)(Bb + (wn + nt * 16 + l15) * 32 + rcx);
#pragma unroll
        for (int mt = 0; mt < 4; mt++)
#pragma unroll
            for (int nt = 0; nt < 4; nt++)
                acc[mt][nt] = __builtin_amdgcn_mfma_f32_16x16x32_bf16(af[mt], bf[nt], acc[mt][nt], 0, 0, 0);
    };

    const int NS = K / 32;
    STAGE3(0, 0);
    __syncthreads();
#pragma unroll 1
    for (int ks = 0; ks < NS; ks++) {
        if (ks + 1 < NS) STAGE3((ks + 1) & 1, (ks + 1) * 32);
        compute(ks & 1);
        __syncthreads();
    }
#undef STAGE3

#pragma unroll
    for (int mt = 0; mt < 4; mt++) {
#pragma unroll
        for (int r = 0; r < 4; r++) {
            int gm = m0 + wm + mt * 16 + quad * 4 + r;
            if (gm < M) {
                if (SH) {
                    size_t o = (size_t)gm * CDIM + n0 + wn + l15;
#pragma unroll
                    for (int nt = 0; nt < 4; nt++)
                        Out[o + nt * 16] = acc[mt][nt][r];
                } else {
                    size_t o = (size_t)(base + gm) * CDIM + n0 + wn + l15;
#pragma unroll
                    for (int nt = 0; nt < 4; nt++)
                        pE[o + nt * 16] = f2bf(acc[mt][nt][r]);
                }
            }
        }
    }
}

// ---------------- combine: out[t] += w0*pE[s0] + w1*pE[s1] ----------------
__global__ __launch_bounds__(256) void combine_kernel(
    float* __restrict__ Out, const unsigned short* __restrict__ pE,
    const int* __restrict__ tokSlot, const float* __restrict__ rowW) {
    const int t = blockIdx.x;
    const int c = threadIdx.x * 4;
    const int s0 = tokSlot[2 * t], s1 = tokSlot[2 * t + 1];
    const float w0 = rowW[s0], w1 = rowW[s1];
    float* op = Out + (size_t)t * CDIM + c;
    float4 o = *(float4*)op;
    ushort4 a = *(const ushort4*)(pE + (size_t)s0 * CDIM + c);
    ushort4 b = *(const ushort4*)(pE + (size_t)s1 * CDIM + c);
    o.x += w0 * bf2f(a.x) + w1 * bf2f(b.x);
    o.y += w0 * bf2f(a.y) + w1 * bf2f(b.y);
    o.z += w0 * bf2f(a.z) + w1 * bf2f(b.z);
    o.w += w0 * bf2f(a.w) + w1 * bf2f(b.w);
    *(float4*)op = o;
}

// ---------------- launch ----------------

extern "C" void kernel_launch(void* const* d_in, const int* in_sizes, int n_in,
                              void* d_out, int out_size, void* d_ws, size_t ws_size,
                              hipStream_t stream) {
    const float* x   = (const float*)d_in[0];
    const float* Wg  = (const float*)d_in[1];
    const float* W1  = (const float*)d_in[2];
    const float* W2  = (const float*)d_in[3];
    const float* W3  = (const float*)d_in[4];
    const float* Ws1 = (const float*)d_in[5];
    const float* Ws2 = (const float*)d_in[6];
    const float* Ws3 = (const float*)d_in[7];
    float* out = (float*)d_out;

    char* p = (char*)d_ws;
    auto carve = [&](size_t bytes) {
        char* r = p;
        p += (bytes + 255) & ~(size_t)255;
        return r;
    };
    unsigned short* xb   = (unsigned short*)carve((size_t)NTOK * CDIM * 2);
    unsigned short* w1t  = (unsigned short*)carve((size_t)NEXP * HDIM * CDIM * 2);
    unsigned short* w2t  = (unsigned short*)carve((size_t)NEXP * HDIM * CDIM * 2);
    unsigned short* w3t  = (unsigned short*)carve((size_t)NEXP * CDIM * HDIM * 2);
    unsigned short* ws1t = (unsigned short*)carve((size_t)HSDIM * CDIM * 2);
    unsigned short* ws2t = (unsigned short*)carve((size_t)HSDIM * CDIM * 2);
    unsigned short* ws3t = (unsigned short*)carve((size_t)CDIM * HSDIM * 2);
    unsigned short* hE   = (unsigned short*)carve((size_t)2 * NTOK * HDIM * 2);
    unsigned short* hS   = (unsigned short*)carve((size_t)NTOK * HSDIM * 2);
    int*   idxK   = (int*)carve((size_t)NTOK * 2 * 4);
    float* probK  = (float*)carve((size_t)NTOK * 2 * 4);
    int*   rowT   = (int*)carve((size_t)2 * NTOK * 4);
    float* rowW   = (float*)carve((size_t)2 * NTOK * 4);
    int*   tokSlot= (int*)carve((size_t)2 * NTOK * 4);
    int*   meta   = (int*)carve(256);

    // expert partials (bf16, 2N x C = 33.5 MB) alias the w1t+w2t region,
    // which is dead after gemm12 completes (stream-ordered before gemm3).
    unsigned short* pE = w1t;

    hipMemsetAsync(meta, 0, 256, stream);
    prep_kernel<<<P_TOTAL, 256, 0, stream>>>(
        x, Wg, W1, W2, W3, Ws1, Ws2, Ws3,
        xb, w1t, w2t, w3t, ws1t, ws2t, ws3t, idxK, probK, meta);
    offsets_kernel<<<1, 1, 0, stream>>>(meta);
    fill_kernel<<<NTOK / 256, 256, 0, stream>>>(idxK, probK, meta, rowT, rowW, tokSlot);

    gemm12_kernel<<<3520 + 2816, 256, 0, stream>>>(
        xb, w1t, w2t, ws1t, ws2t, hE, hS, rowT, meta);
    gemm3_kernel<<<512 + 1280, 256, 0, stream>>>(
        hE, hS, w3t, ws3t, out, pE, rowT, rowW, meta);
    combine_kernel<<<NTOK, 256, 0, stream>>>(out, pE, tokSlot, rowW);
}

// Round 5
// 810.167 us; speedup vs baseline: 1.0813x; 1.0201x over previous
//
#include <hip/hip_runtime.h>
#include <cstdint>

#define NTOK 8192
#define CDIM 1024
#define HDIM 1408
#define HSDIM 2816
#define NEXP 8

typedef __attribute__((ext_vector_type(8))) short s8v;
typedef __attribute__((ext_vector_type(4))) float f4v;
typedef __attribute__((ext_vector_type(8))) unsigned short u16x8;

__device__ __forceinline__ unsigned short f2bf(float f) {
    unsigned int u = __float_as_uint(f);
    unsigned int r = (u + 0x7fffu + ((u >> 16) & 1u)) >> 16;  // RNE
    return (unsigned short)r;
}
__device__ __forceinline__ float bf2f(unsigned short u) {
    return __uint_as_float(((unsigned int)u) << 16);
}

__device__ __forceinline__ void gld_lds16(const unsigned short* g, unsigned short* l) {
    __builtin_amdgcn_global_load_lds(
        (const __attribute__((address_space(1))) void*)g,
        (__attribute__((address_space(3))) void*)l, 16, 0, 0);
}

// ---------------- fused prep kernel ----------------
// One launch covering: router (wave/token), x->bf16 cvt, and all 4 weight
// transposes. All parts are independent; selected by blockIdx range.

#define P_RTR 2048                  // 8192 tokens, 4 waves/block
#define P_CVT 8192                  // NTOK*CDIM/4 float4 / 256
#define P_T1 (22 * 16 * 16)         // W1,W2 (5632)
#define P_T2 (16 * 22 * 8)          // W3 (2816)
#define P_T3 (44 * 16 * 2)          // Ws1,Ws2 (1408)
#define P_T4 (16 * 44 * 1)          // Ws3 (704)
#define P_TOTAL (P_RTR + P_CVT + P_T1 + P_T2 + P_T3 + P_T4)

__device__ __forceinline__ void transpose_tile(
    float (*T)[68], const float* __restrict__ in, unsigned short* __restrict__ out,
    int R, int Cc, int bx, int by) {
    const int t = threadIdx.x;
    const int r0 = by * 64, c0 = bx * 64;
    {
        const int rl = t >> 2, cq = t & 3;
        const float* src = in + (size_t)(r0 + rl) * Cc + c0;
#pragma unroll
        for (int i = 0; i < 4; i++) {
            float4 v = *(const float4*)(src + (cq + 4 * i) * 4);
            *(float4*)&T[rl][(cq + 4 * i) * 4] = v;
        }
    }
    __syncthreads();
    {
        const int cl = t >> 2, rq = t & 3;
        unsigned short* dst = out + (size_t)(c0 + cl) * R + r0 + rq * 16;
        u16x8 lo, hi;
#pragma unroll
        for (int j = 0; j < 8; j++) lo[j] = f2bf(T[rq * 16 + j][cl]);
#pragma unroll
        for (int j = 0; j < 8; j++) hi[j] = f2bf(T[rq * 16 + 8 + j][cl]);
        *(u16x8*)dst = lo;
        *(u16x8*)(dst + 8) = hi;
    }
}

__global__ __launch_bounds__(256) void prep_kernel(
    const float* __restrict__ x, const float* __restrict__ Wg,
    const float* __restrict__ W1, const float* __restrict__ W2, const float* __restrict__ W3,
    const float* __restrict__ Ws1, const float* __restrict__ Ws2, const float* __restrict__ Ws3,
    unsigned short* __restrict__ xb,
    unsigned short* __restrict__ w1t, unsigned short* __restrict__ w2t,
    unsigned short* __restrict__ w3t,
    unsigned short* __restrict__ ws1t, unsigned short* __restrict__ ws2t,
    unsigned short* __restrict__ ws3t,
    int* __restrict__ idxK, float* __restrict__ probK, int* __restrict__ meta) {
    __shared__ float T[64][68];
    int bid = blockIdx.x;
    const int tid = threadIdx.x;

    if (bid < P_RTR) {
        // ---- router: one wave per token ----
        const int t = bid * 4 + (tid >> 6);
        const int lane = tid & 63;
        const float* xr = x + (size_t)t * CDIM;
        float acc[NEXP];
#pragma unroll
        for (int e = 0; e < NEXP; e++) acc[e] = 0.f;
        for (int c = lane; c < CDIM; c += 64) {
            float xv = xr[c];
            const float* wr = Wg + c * NEXP;
#pragma unroll
            for (int e = 0; e < NEXP; e++) acc[e] += xv * wr[e];
        }
#pragma unroll
        for (int e = 0; e < NEXP; e++)
            for (int off = 32; off > 0; off >>= 1)
                acc[e] += __shfl_down(acc[e], off, 64);
        if (lane == 0) {
            int b0 = 0; float v0 = acc[0];
#pragma unroll
            for (int e = 1; e < NEXP; e++) if (acc[e] > v0) { v0 = acc[e]; b0 = e; }
            int b1 = -1; float v1 = -1e30f;
#pragma unroll
            for (int e = 0; e < NEXP; e++) if (e != b0 && acc[e] > v1) { v1 = acc[e]; b1 = e; }
            float p0 = 1.f / (1.f + __expf(v1 - v0));
            idxK[2 * t] = b0; idxK[2 * t + 1] = b1;
            probK[2 * t] = p0; probK[2 * t + 1] = 1.f - p0;
            atomicAdd(&meta[b0], 1);
            atomicAdd(&meta[b1], 1);
        }
        return;
    }
    bid -= P_RTR;
    if (bid < P_CVT) {
        // ---- x -> bf16 ----
        const int i = bid * 256 + tid;
        float4 v = ((const float4*)x)[i];
        ushort4 o;
        o.x = f2bf(v.x); o.y = f2bf(v.y); o.z = f2bf(v.z); o.w = f2bf(v.w);
        ((ushort4*)xb)[i] = o;
        return;
    }
    bid -= P_CVT;
    if (bid < P_T1) {
        // ---- W1/W2 [e][C][H] -> [e][H][C] ----
        const int bx = bid % 22, by = (bid / 22) % 16, z = bid / (22 * 16);
        const float* in = (z < 8) ? W1 : W2;
        unsigned short* out = (z < 8) ? w1t : w2t;
        const int zz = (z < 8) ? z : z - 8;
        const size_t bs = (size_t)CDIM * HDIM;
        transpose_tile(T, in + zz * bs, out + zz * bs, CDIM, HDIM, bx, by);
        return;
    }
    bid -= P_T1;
    if (bid < P_T2) {
        // ---- W3 [e][H][C] -> [e][C][H] ----
        const int bx = bid % 16, by = (bid / 16) % 22, z = bid / (16 * 22);
        const size_t bs = (size_t)HDIM * CDIM;
        transpose_tile(T, W3 + z * bs, w3t + z * bs, HDIM, CDIM, bx, by);
        return;
    }
    bid -= P_T2;
    if (bid < P_T3) {
        // ---- Ws1/Ws2 [C][HS] -> [HS][C] ----
        const int bx = bid % 44, by = (bid / 44) % 16, z = bid / (44 * 16);
        const float* in = (z == 0) ? Ws1 : Ws2;
        unsigned short* out = (z == 0) ? ws1t : ws2t;
        transpose_tile(T, in, out, CDIM, HSDIM, bx, by);
        return;
    }
    bid -= P_T3;
    {
        // ---- Ws3 [HS][C] -> [C][HS] ----
        const int bx = bid % 16, by = bid / 16;
        transpose_tile(T, Ws3, ws3t, HSDIM, CDIM, bx, by);
    }
}

// meta: [0..7] counts, [8..15] offsets, [16..23] cursor
__global__ void offsets_kernel(int* meta) {
    int s = 0;
    for (int e = 0; e < NEXP; e++) { meta[8 + e] = s; meta[16 + e] = s; s += meta[e]; }
}

__global__ void fill_kernel(const int* __restrict__ idxK, const float* __restrict__ probK,
                            int* __restrict__ meta, int* __restrict__ rowT, float* __restrict__ rowW,
                            int* __restrict__ tokSlot) {
    int t = blockIdx.x * 256 + threadIdx.x;
    if (t >= NTOK) return;
#pragma unroll
    for (int k = 0; k < 2; k++) {
        int e = idxK[2 * t + k];
        int p = atomicAdd(&meta[16 + e], 1);
        rowT[p] = t;
        rowW[p] = probK[2 * t + k];
        tokSlot[2 * t + k] = p;
    }
}

// ---------------- fused gate GEMM: H = silu(A@W1) * (A@W2), m201 8-phase ----
// BM=256, virtual BN'=256 (B1/B2 interleaved at 16-col granularity -> 128 real
// H-cols, silu pairs intra-wave), BK=64, 8 waves (2Mx4N), 128 KB LDS dbuf.
// Region-death staging: s0-A dead after P3 (staged P4,P5), s0-B after P4
// (P6,P7), s1-A after P7 (P8,P1'), s1-B after P8 (P2',P3'). Counted
// vmcnt(2)+barrier at P4 and P8 only. Bank swizzle carried on global source.
__global__ __launch_bounds__(512, 2) void gemm12_kernel(
    const unsigned short* __restrict__ xb,
    const unsigned short* __restrict__ w1, const unsigned short* __restrict__ w2,
    const unsigned short* __restrict__ ws1, const unsigned short* __restrict__ ws2,
    unsigned short* __restrict__ hE, unsigned short* __restrict__ hS,
    const int* __restrict__ rowT, const int* __restrict__ meta) {
    const int id = blockIdx.x;
    int z, m0, n0; bool SH;
    if (id < 880) { SH = false; z = id & 7; int q = id >> 3; m0 = (q % 10) * 256; n0 = (q / 10) * 128; }
    else          { SH = true;  z = 8; int q = id - 880; m0 = (q & 31) * 256; n0 = (q >> 5) * 128; }
    const int M = SH ? NTOK : meta[z];
    const int base = SH ? 0 : meta[8 + z];
    if (m0 >= M) return;

    const unsigned short* B1 = SH ? ws1 : w1 + (size_t)z * HDIM * CDIM;
    const unsigned short* B2 = SH ? ws2 : w2 + (size_t)z * HDIM * CDIM;

    __shared__ unsigned short L[65536];  // 128 KB

    const int tid = threadIdx.x;
    const int srow = tid >> 3;                        // 0..63
    const int cg = ((tid & 7) ^ (srow & 7)) << 3;     // pre-swizzled global chunk

    // staging pointers: A rows and interleaved-B' rows, per (half h, unit u)
    const unsigned short* pA[2][2];
    const unsigned short* pB[2][2];
#pragma unroll
    for (int h = 0; h < 2; h++)
#pragma unroll
        for (int u = 0; u < 2; u++) {
            int lr = h * 128 + u * 64 + srow;
            int am = m0 + lr; am = am < M ? am : M - 1;
            int gr = SH ? am : rowT[base + am];
            pA[h][u] = xb + (size_t)gr * CDIM + cg;
            int n = lr;  // virtual B' row
            int hcol = n0 + ((n >> 5) << 4) + (n & 15);
            pB[h][u] = (((n >> 4) & 1) ? B2 : B1) + (size_t)hcol * CDIM + cg;
        }

    const int w = tid >> 6, lane = tid & 63;
    const int wr = w >> 2, wc = w & 3;
    const int quad = lane >> 4, l15 = lane & 15;
    int ck[2];
    ck[0] = (quad ^ (l15 & 7)) << 3;
    ck[1] = ((4 + quad) ^ (l15 & 7)) << 3;
    const int ArdBase = wr * 8192 + l15 * 64;
    const int BrdBase = 16384 + (wc >> 1) * 8192 + ((wc & 1) * 64 + l15) * 64;

    f4v acc[8][4];
#pragma unroll
    for (int i = 0; i < 8; i++)
#pragma unroll
        for (int j = 0; j < 4; j++) {
            f4v zz = {0.f, 0.f, 0.f, 0.f};
            acc[i][j] = zz;
        }

    s8v aF[4][2], bF[2][2];

    auto SA = [&](int s, int h, int kt) {
        gld_lds16(pA[h][0] + (size_t)kt * 64, L + s * 32768 + h * 8192 + tid * 8);
        gld_lds16(pA[h][1] + (size_t)kt * 64, L + s * 32768 + h * 8192 + 4096 + tid * 8);
    };
    auto SB = [&](int s, int h, int kt) {
        gld_lds16(pB[h][0] + (size_t)kt * 64, L + s * 32768 + 16384 + h * 8192 + tid * 8);
        gld_lds16(pB[h][1] + (size_t)kt * 64, L + s * 32768 + 16384 + h * 8192 + 4096 + tid * 8);
    };
    auto RA = [&](int s, int mb) {
#pragma unroll
        for (int j = 0; j < 4; j++)
#pragma unroll
            for (int k = 0; k < 2; k++)
                aF[j][k] = *(const s8v*)(L + s * 32768 + ArdBase + (mb + j) * 1024 + ck[k]);
    };
    auto RB = [&](int s, int nb) {
#pragma unroll
        for (int j = 0; j < 2; j++)
#pragma unroll
            for (int k = 0; k < 2; k++)
                bF[j][k] = *(const s8v*)(L + s * 32768 + BrdBase + (nb + j) * 1024 + ck[k]);
    };
    auto MF = [&](int mb, int nb) {
#pragma unroll
        for (int k = 0; k < 2; k++)
#pragma unroll
            for (int j = 0; j < 4; j++)
#pragma unroll
                for (int n = 0; n < 2; n++)
                    acc[mb + j][nb + n] = __builtin_amdgcn_mfma_f32_16x16x32_bf16(
                        aF[j][k], bF[n][k], acc[mb + j][nb + n], 0, 0, 0);
    };

#define BAR() __builtin_amdgcn_s_barrier()
#define LGKM0() do { asm volatile("s_waitcnt lgkmcnt(0)" ::: "memory"); \
                     __builtin_amdgcn_sched_barrier(0); } while (0)
#define VM2() do { asm volatile("s_waitcnt vmcnt(2)" ::: "memory"); \
                   __builtin_amdgcn_sched_barrier(0); } while (0)
#define PRIO1() __builtin_amdgcn_s_setprio(1)
#define PRIO0() __builtin_amdgcn_s_setprio(0)

    // prologue: tile0 -> slot0 (4 half-tiles), tile1 A0 -> slot1
    SA(0, 0, 0); SA(0, 1, 0); SB(0, 0, 0); SB(0, 1, 0); SA(1, 0, 1);
    VM2(); BAR();

#pragma unroll 1
    for (int i = 0; i < 8; i++) {
        const int k1 = 2 * i + 1;
        const int k2 = (2 * i + 2 < 16) ? 2 * i + 2 : 15;
        const int k3 = (2 * i + 3 < 16) ? 2 * i + 3 : 15;
        // P1: s0 quadrant (m0-3, n0-1)
        RA(0, 0); RB(0, 0); SA(1, 1, k1);
        BAR(); LGKM0(); PRIO1(); MF(0, 0); PRIO0(); BAR();
        // P2: (m0-3, n2-3)
        RB(0, 2); SB(1, 0, k1);
        BAR(); LGKM0(); PRIO1(); MF(0, 2); PRIO0(); BAR();
        // P3: (m4-7, n0-1)
        RA(0, 4); RB(0, 0); SB(1, 1, k1);
        BAR(); LGKM0(); PRIO1(); MF(4, 0); PRIO0(); BAR();
        // P4: (m4-7, n2-3) + counted wait for slot1's tile
        RB(0, 2); SA(0, 0, k2);
        BAR(); LGKM0(); PRIO1(); MF(4, 2); PRIO0(); VM2(); BAR();
        // P5: s1 quadrant (m0-3, n0-1)
        RA(1, 0); RB(1, 0); SA(0, 1, k2);
        BAR(); LGKM0(); PRIO1(); MF(0, 0); PRIO0(); BAR();
        // P6: (m0-3, n2-3)
        RB(1, 2); SB(0, 0, k2);
        BAR(); LGKM0(); PRIO1(); MF(0, 2); PRIO0(); BAR();
        // P7: (m4-7, n0-1)
        RA(1, 4); RB(1, 0); SB(0, 1, k2);
        BAR(); LGKM0(); PRIO1(); MF(4, 0); PRIO0(); BAR();
        // P8: (m4-7, n2-3) + counted wait for slot0's next tile
        RB(1, 2); SA(1, 0, k3);
        BAR(); LGKM0(); PRIO1(); MF(4, 2); PRIO0(); VM2(); BAR();
    }
    asm volatile("s_waitcnt vmcnt(0)" ::: "memory");

#undef BAR
#undef LGKM0
#undef VM2
#undef PRIO1
#undef PRIO0

    // epilogue: silu(B1-col) * B2-col pairs; wave covers 128 rows x 32 H-cols
#pragma unroll
    for (int mf = 0; mf < 8; mf++) {
#pragma unroll
        for (int r = 0; r < 4; r++) {
            int gm = m0 + wr * 128 + mf * 16 + quad * 4 + r;
            if (gm < M) {
                unsigned short* hrow = SH ? hS + (size_t)gm * HSDIM
                                          : hE + (size_t)(base + gm) * HDIM;
                const int cbase = n0 + wc * 32;
#pragma unroll
                for (int p = 0; p < 2; p++) {
                    float z1 = acc[mf][2 * p][r];
                    float z2 = acc[mf][2 * p + 1][r];
                    float hv = (z1 / (1.f + __expf(-z1))) * z2;
                    hrow[cbase + p * 16 + l15] = f2bf(hv);
                }
            }
        }
    }
}

// ---------------- merged down-proj GEMM (R1-verified form) ----------------
// Longest-job-first: shared blocks (K=2816, 2x work) dispatch at ids [0,512).
__global__ __launch_bounds__(256) void gemm3_kernel(
    const unsigned short* __restrict__ hE, const unsigned short* __restrict__ hS,
    const unsigned short* __restrict__ w3, const unsigned short* __restrict__ ws3,
    float* __restrict__ Out, unsigned short* __restrict__ pE,
    const int* __restrict__ rowT, const float* __restrict__ rowW, const int* __restrict__ meta) {
    const int id = blockIdx.x;
    int z, m0, n0; bool SH;
    if (id < 512) { SH = true;  z = 8; int q = id; m0 = (q & 63) * 128; n0 = (q >> 6) * 128; }
    else          { SH = false; int r = id - 512; z = r & 7; int q = r >> 3; m0 = (q % 20) * 128; n0 = (q / 20) * 128; }
    const int M = SH ? NTOK : meta[z];
    const int base = SH ? 0 : meta[8 + z];
    if (m0 >= M) return;
    const int K = SH ? HSDIM : HDIM;
    const unsigned short* A = SH ? hS : hE;
    const unsigned short* B = SH ? ws3 : w3 + (size_t)z * CDIM * HDIM;

    __shared__ unsigned short L[16384];

    const int tid = threadIdx.x;
    const int srow = tid >> 2;
    const int key = (tid >> 3) & 3;
    const int co = ((tid & 3) ^ key) << 3;

    int am0 = m0 + srow;       am0 = am0 < M ? am0 : M - 1;
    int am1 = m0 + 64 + srow;  am1 = am1 < M ? am1 : M - 1;
    const unsigned short* a0p = A + (size_t)(base + am0) * K + co;
    const unsigned short* a1p = A + (size_t)(base + am1) * K + co;
    const unsigned short* b0p = B + (size_t)(n0 + srow) * K + co;
    const unsigned short* b1p = B + (size_t)(n0 + 64 + srow) * K + co;

    const int w = tid >> 6, lane = tid & 63;
    const int wm = (w >> 1) * 64, wn = (w & 1) * 64;
    const int quad = lane >> 4, l15 = lane & 15;
    const int rcx = (quad ^ ((l15 >> 1) & 3)) << 3;

    f4v acc[4][4];
#pragma unroll
    for (int i = 0; i < 4; i++)
#pragma unroll
        for (int j = 0; j < 4; j++) {
            f4v zz = {0.f, 0.f, 0.f, 0.f};
            acc[i][j] = zz;
        }

#define STAGE3(b, k0) do { \
        gld_lds16(a0p + (k0), L + (b) * 4096 + tid * 8); \
        gld_lds16(a1p + (k0), L + (b) * 4096 + 2048 + tid * 8); \
        gld_lds16(b0p + (k0), L + 8192 + (b) * 4096 + tid * 8); \
        gld_lds16(b1p + (k0), L + 8192 + (b) * 4096 + 2048 + tid * 8); } while (0)

    auto compute = [&](int b) {
        const unsigned short* Ab = L + b * 4096;
        const unsigned short* Bb = L + 8192 + b * 4096;
        s8v af[4], bf[4];
#pragma unroll
        for (int mt = 0; mt < 4; mt++)
            af[mt] = *(const s8v*)(Ab + (wm + mt * 16 + l15) * 32 + rcx);
#pragma unroll
        for (int nt = 0; nt < 4; nt++)
            bf[nt] = *(const s8v*)(Bb + (wn + nt * 16 + l15) * 32 + rcx);
#pragma unroll
        for (int mt = 0; mt < 4; mt++)
#pragma unroll
            for (int nt = 0; nt < 4; nt++)
                acc[mt][nt] = __builtin_amdgcn_mfma_f32_16x16x32_bf16(af[mt], bf[nt], acc[mt][nt], 0, 0, 0);
    };

    const int NS = K / 32;
    STAGE3(0, 0);
    __syncthreads();
#pragma unroll 1
    for (int ks = 0; ks < NS; ks++) {
        if (ks + 1 < NS) STAGE3((ks + 1) & 1, (ks + 1) * 32);
        compute(ks & 1);
        __syncthreads();
    }
#undef STAGE3

#pragma unroll
    for (int mt = 0; mt < 4; mt++) {
#pragma unroll
        for (int r = 0; r < 4; r++) {
            int gm = m0 + wm + mt * 16 + quad * 4 + r;
            if (gm < M) {
                if (SH) {
                    size_t o = (size_t)gm * CDIM + n0 + wn + l15;
#pragma unroll
                    for (int nt = 0; nt < 4; nt++)
                        Out[o + nt * 16] = acc[mt][nt][r];
                } else {
                    size_t o = (size_t)(base + gm) * CDIM + n0 + wn + l15;
#pragma unroll
                    for (int nt = 0; nt < 4; nt++)
                        pE[o + nt * 16] = f2bf(acc[mt][nt][r]);
                }
            }
        }
    }
}

// ---------------- combine: out[t] += w0*pE[s0] + w1*pE[s1] ----------------
__global__ __launch_bounds__(256) void combine_kernel(
    float* __restrict__ Out, const unsigned short* __restrict__ pE,
    const int* __restrict__ tokSlot, const float* __restrict__ rowW) {
    const int t = blockIdx.x;
    const int c = threadIdx.x * 4;
    const int s0 = tokSlot[2 * t], s1 = tokSlot[2 * t + 1];
    const float w0 = rowW[s0], w1 = rowW[s1];
    float* op = Out + (size_t)t * CDIM + c;
    float4 o = *(float4*)op;
    ushort4 a = *(const ushort4*)(pE + (size_t)s0 * CDIM + c);
    ushort4 b = *(const ushort4*)(pE + (size_t)s1 * CDIM + c);
    o.x += w0 * bf2f(a.x) + w1 * bf2f(b.x);
    o.y += w0 * bf2f(a.y) + w1 * bf2f(b.y);
    o.z += w0 * bf2f(a.z) + w1 * bf2f(b.z);
    o.w += w0 * bf2f(a.w) + w1 * bf2f(b.w);
    *(float4*)op = o;
}

// ---------------- launch ----------------

extern "C" void kernel_launch(void* const* d_in, const int* in_sizes, int n_in,
                              void* d_out, int out_size, void* d_ws, size_t ws_size,
                              hipStream_t stream) {
    const float* x   = (const float*)d_in[0];
    const float* Wg  = (const float*)d_in[1];
    const float* W1  = (const float*)d_in[2];
    const float* W2  = (const float*)d_in[3];
    const float* W3  = (const float*)d_in[4];
    const float* Ws1 = (const float*)d_in[5];
    const float* Ws2 = (const float*)d_in[6];
    const float* Ws3 = (const float*)d_in[7];
    float* out = (float*)d_out;

    char* p = (char*)d_ws;
    auto carve = [&](size_t bytes) {
        char* r = p;
        p += (bytes + 255) & ~(size_t)255;
        return r;
    };
    unsigned short* xb   = (unsigned short*)carve((size_t)NTOK * CDIM * 2);
    unsigned short* w1t  = (unsigned short*)carve((size_t)NEXP * HDIM * CDIM * 2);
    unsigned short* w2t  = (unsigned short*)carve((size_t)NEXP * HDIM * CDIM * 2);
    unsigned short* w3t  = (unsigned short*)carve((size_t)NEXP * CDIM * HDIM * 2);
    unsigned short* ws1t = (unsigned short*)carve((size_t)HSDIM * CDIM * 2);
    unsigned short* ws2t = (unsigned short*)carve((size_t)HSDIM * CDIM * 2);
    unsigned short* ws3t = (unsigned short*)carve((size_t)CDIM * HSDIM * 2);
    unsigned short* hE   = (unsigned short*)carve((size_t)2 * NTOK * HDIM * 2);
    unsigned short* hS   = (unsigned short*)carve((size_t)NTOK * HSDIM * 2);
    int*   idxK   = (int*)carve((size_t)NTOK * 2 * 4);
    float* probK  = (float*)carve((size_t)NTOK * 2 * 4);
    int*   rowT   = (int*)carve((size_t)2 * NTOK * 4);
    float* rowW   = (float*)carve((size_t)2 * NTOK * 4);
    int*   tokSlot= (int*)carve((size_t)2 * NTOK * 4);
    int*   meta   = (int*)carve(256);

    // expert partials (bf16, 2N x C = 33.5 MB) alias the w1t+w2t region,
    // which is dead after gemm12 completes (stream-ordered before gemm3).
    unsigned short* pE = w1t;

    hipMemsetAsync(meta, 0, 256, stream);
    prep_kernel<<<P_TOTAL, 256, 0, stream>>>(
        x, Wg, W1, W2, W3, Ws1, Ws2, Ws3,
        xb, w1t, w2t, w3t, ws1t, ws2t, ws3t, idxK, probK, meta);
    offsets_kernel<<<1, 1, 0, stream>>>(meta);
    fill_kernel<<<NTOK / 256, 256, 0, stream>>>(idxK, probK, meta, rowT, rowW, tokSlot);

    gemm12_kernel<<<880 + 704, 512, 0, stream>>>(
        xb, w1t, w2t, ws1t, ws2t, hE, hS, rowT, meta);
    gemm3_kernel<<<512 + 1280, 256, 0, stream>>>(
        hE, hS, w3t, ws3t, out, pE, rowT, rowW, meta);
    combine_kernel<<<NTOK, 256, 0, stream>>>(out, pE, tokSlot, rowW);
}